// Round 7
// baseline (224.092 us; speedup 1.0000x reference)
//
#include <hip/hip_runtime.h>
#include <hip/hip_bf16.h>
#include <math.h>

typedef __bf16 bf16;
typedef __attribute__((ext_vector_type(8))) __bf16 bf16x8;
typedef __attribute__((ext_vector_type(4))) __bf16 bf16x4;
typedef __attribute__((ext_vector_type(2))) __bf16 bf16x2;
typedef __attribute__((ext_vector_type(4))) float f32x4;

#define LOG2E 1.4426950408889634f

__device__ __forceinline__ void gload16(const bf16* g, bf16* l) {
  __builtin_amdgcn_global_load_lds(
      (const __attribute__((address_space(1))) void*)g,
      (__attribute__((address_space(3))) void*)l, 16, 0, 0);
}

__device__ __forceinline__ unsigned packbf2(float a, float b) {
  bf16x2 v = { (bf16)a, (bf16)b };
  return __builtin_bit_cast(unsigned, v);
}

// ---------------------------------------------------------------- fused cast fp32 -> bf16 (5 tensors, 1 launch)
struct CastSegs { const float* src[5]; bf16* dst[5]; };

__global__ void fused_cast_kernel(CastSegs segs) {
  const int e0 = 786432, e1 = 1228800, e2 = 1376256, e3 = 1769472, e4 = 2162688;
  int i = blockIdx.x * blockDim.x + threadIdx.x;
  int stride = gridDim.x * blockDim.x;
  for (; i < e4; i += stride) {
    int s = 0, base = 0;
    if (i >= e0) { s = 1; base = e0; }
    if (i >= e1) { s = 2; base = e1; }
    if (i >= e2) { s = 3; base = e2; }
    if (i >= e3) { s = 4; base = e3; }
    float4 v = ((const float4*)segs.src[s])[i - base];
    bf16x4 o = { (bf16)v.x, (bf16)v.y, (bf16)v.z, (bf16)v.w };
    ((bf16x4*)segs.dst[s])[i - base] = o;
  }
}

// ---------------------------------------------------------------- GEMM 128x128 (m97 structure)
// MODE 0: out bf16 = acc + bias
// MODE 2: out bf16 = gelu_erf(acc + bias)
// MODE 3: qkv writer: cols <1536 -> bf16 to out; cols >=1536 (V) -> transposed to vt
template<int MODE>
__launch_bounds__(256)
__global__ void gemm_kernel(const bf16* __restrict__ A, const bf16* __restrict__ W,
                            const float* __restrict__ bias, bf16* __restrict__ vt,
                            void* __restrict__ out, int K, int O) {
  __shared__ bf16 As[128 * 64];
  __shared__ bf16 Bs[128 * 64];
  const int t    = threadIdx.x;
  const int lane = t & 63;
  const int wave = t >> 6;
  const int wr = (wave >> 1) * 64;
  const int wc = (wave & 1) * 64;
  const int n0 = blockIdx.y * 128;
  const int o0 = blockIdx.x * 128;

  f32x4 zero = {0.f, 0.f, 0.f, 0.f};
  f32x4 acc[4][4];
#pragma unroll
  for (int m = 0; m < 4; m++)
#pragma unroll
    for (int n = 0; n < 4; n++) acc[m][n] = zero;

  const int fr  = lane & 15;
  const int fg8 = (lane >> 4) * 8;

  for (int k0 = 0; k0 < K; k0 += 64) {
    __syncthreads();
#pragma unroll
    for (int c = 0; c < 4; c++) {
      int f = c * 256 + t;
      int row = f >> 3;
      int col = (f & 7) * 8;
      gload16(&A[(size_t)(n0 + row) * K + k0 + col], &As[f * 8]);
      gload16(&W[(size_t)(o0 + row) * K + k0 + col], &Bs[f * 8]);
    }
    __syncthreads();
#pragma unroll
    for (int kf = 0; kf < 2; kf++) {
      bf16x8 a[4], b[4];
#pragma unroll
      for (int m = 0; m < 4; m++) a[m] = *(const bf16x8*)&As[(wr + m * 16 + fr) * 64 + kf * 32 + fg8];
#pragma unroll
      for (int n = 0; n < 4; n++) b[n] = *(const bf16x8*)&Bs[(wc + n * 16 + fr) * 64 + kf * 32 + fg8];
#pragma unroll
      for (int m = 0; m < 4; m++)
#pragma unroll
        for (int n = 0; n < 4; n++)
          acc[m][n] = __builtin_amdgcn_mfma_f32_16x16x32_bf16(a[m], b[n], acc[m][n], 0, 0, 0);
    }
  }

  const int fg4 = (lane >> 4) * 4;
#pragma unroll
  for (int m = 0; m < 4; m++) {
#pragma unroll
    for (int n = 0; n < 4; n++) {
      int col = o0 + wc + n * 16 + fr;
      float bv = bias[col];
      if constexpr (MODE == 3) {
        if (col >= 1536) {
          int c = col - 1536;
          int h = c / 96;
          int hd = c - h * 96;
          int row0 = n0 + wr + m * 16 + fg4;
          int b = row0 >> 11;
          int token = row0 & 2047;
          bf16x4 ov;
#pragma unroll
          for (int r = 0; r < 4; r++) ov[r] = (bf16)(acc[m][n][r] + bv);
          *(bf16x4*)&vt[((size_t)((b * 8 + h) * 96 + hd)) * 2048 + token] = ov;
          continue;
        }
      }
#pragma unroll
      for (int r = 0; r < 4; r++) {
        int row = n0 + wr + m * 16 + fg4 + r;
        float v = acc[m][n][r] + bv;
        if constexpr (MODE == 2) {
          v = 0.5f * v * (1.0f + erff(v * 0.70710678118654752f));
          ((bf16*)out)[(size_t)row * O + col] = (bf16)v;
        } else {
          ((bf16*)out)[(size_t)row * O + col] = (bf16)v;
        }
      }
    }
  }
}

// ---------------------------------------------------------------- GEMM 128x64 (grid-filling): f32 out = acc + bias + res
__launch_bounds__(256)
__global__ void gemmW_kernel(const bf16* __restrict__ A, const bf16* __restrict__ W,
                             const float* __restrict__ bias, const float* __restrict__ res,
                             float* __restrict__ out, int K, int O) {
  __shared__ bf16 As[128 * 64];
  __shared__ bf16 Bs[64 * 64];
  const int t    = threadIdx.x;
  const int lane = t & 63;
  const int wave = t >> 6;
  const int wr = wave * 32;
  const int n0 = blockIdx.y * 128;
  const int o0 = blockIdx.x * 64;

  f32x4 zero = {0.f, 0.f, 0.f, 0.f};
  f32x4 acc[2][4];
#pragma unroll
  for (int m = 0; m < 2; m++)
#pragma unroll
    for (int n = 0; n < 4; n++) acc[m][n] = zero;

  const int fr  = lane & 15;
  const int fg8 = (lane >> 4) * 8;

  for (int k0 = 0; k0 < K; k0 += 64) {
    __syncthreads();
#pragma unroll
    for (int c = 0; c < 4; c++) {
      int f = c * 256 + t;
      int row = f >> 3;
      int col = (f & 7) * 8;
      gload16(&A[(size_t)(n0 + row) * K + k0 + col], &As[f * 8]);
    }
#pragma unroll
    for (int c = 0; c < 2; c++) {
      int f = c * 256 + t;
      int row = f >> 3;
      int col = (f & 7) * 8;
      gload16(&W[(size_t)(o0 + row) * K + k0 + col], &Bs[f * 8]);
    }
    __syncthreads();
#pragma unroll
    for (int kf = 0; kf < 2; kf++) {
      bf16x8 a[2], b[4];
#pragma unroll
      for (int m = 0; m < 2; m++) a[m] = *(const bf16x8*)&As[(wr + m * 16 + fr) * 64 + kf * 32 + fg8];
#pragma unroll
      for (int n = 0; n < 4; n++) b[n] = *(const bf16x8*)&Bs[(n * 16 + fr) * 64 + kf * 32 + fg8];
#pragma unroll
      for (int m = 0; m < 2; m++)
#pragma unroll
        for (int n = 0; n < 4; n++)
          acc[m][n] = __builtin_amdgcn_mfma_f32_16x16x32_bf16(a[m], b[n], acc[m][n], 0, 0, 0);
    }
  }

  const int fg4 = (lane >> 4) * 4;
#pragma unroll
  for (int m = 0; m < 2; m++) {
#pragma unroll
    for (int n = 0; n < 4; n++) {
      int col = o0 + n * 16 + fr;
      float bv = bias[col];
#pragma unroll
      for (int r = 0; r < 4; r++) {
        int row = n0 + wr + m * 16 + fg4 + r;
        float v = acc[m][n][r] + bv + res[(size_t)row * O + col];
        out[(size_t)row * O + col] = v;
      }
    }
  }
}

// ---------------------------------------------------------------- flash attention, kv-split x2, occupancy-first
// 4 waves x 16 q = 64 q/block; grid 32x8x4 = 1024 blocks -> 4 blocks/CU resident
// (16 waves/CU, 4/SIMD). Single-buffered K/V LDS at stride 104 (<=2-way banks),
// reg-prefetch staging, in-register P exchange, defer-max.
__launch_bounds__(256, 4)
__global__ void attn_kernel(const bf16* __restrict__ qkv, const bf16* __restrict__ vt,
                            const float* __restrict__ bias, float* __restrict__ opart,
                            float* __restrict__ ml) {
  __shared__ bf16 Ks[64 * 104];
  __shared__ bf16 Vs[96 * 104];
  const int t    = threadIdx.x;
  const int lane = t & 63;
  const int wave = t >> 6;
  const int qb = blockIdx.x, h = blockIdx.y;
  const int half = blockIdx.z & 1, b = blockIdx.z >> 1;
  const int kvstart = half * 1024;
  const int q0 = qb * 64 + wave * 16;
  const int fq = lane & 15;
  const int g  = lane >> 4;
  const size_t base = (size_t)b * 2048 * 2304;

  // Q fragments (one 16-q subtile per wave)
  bf16x8 qf[3];
  {
    const bf16* qp = qkv + base + (size_t)(q0 + fq) * 2304 + h * 96;
#pragma unroll
    for (int f = 0; f < 3; f++) qf[f] = *(const bf16x8*)(qp + f * 32 + g * 8);
  }

  // staging geometry (256 threads): K 64x96, V 96x64
  const int krow = t >> 2, kcb = (t & 3) * 24;
  const bf16* kbase = qkv + base + (size_t)kvstart * 2304 + 768 + h * 96;
  const bf16* vbase = vt + (size_t)((b * 8 + h) * 96) * 2048 + kvstart;

  bf16x8 kreg[3], vreg[3];
#pragma unroll
  for (int i = 0; i < 3; i++) {
    kreg[i] = *(const bf16x8*)(kbase + (size_t)krow * 2304 + kcb + i * 8);
    int c = t + 256 * i;
    vreg[i] = *(const bf16x8*)(vbase + (size_t)(c >> 3) * 2048 + (c & 7) * 8);
  }

  float m_run = -1e30f, l_run = 0.f;
  f32x4 zero = {0.f, 0.f, 0.f, 0.f};
  f32x4 o_acc[6];
#pragma unroll
  for (int i = 0; i < 6; i++) o_acc[i] = zero;

  const float scale = 0.10206207261596575f;  // 1/sqrt(96)
  const float* bp = bias + ((size_t)b * 2048 + q0 + fq) * 2048 + kvstart;

  for (int kv0 = 0; kv0 < 1024; kv0 += 64) {
    if (kv0) __syncthreads();  // prev compute done reading LDS
    *(bf16x8*)&Ks[krow * 104 + kcb]      = kreg[0];
    *(bf16x8*)&Ks[krow * 104 + kcb + 8]  = kreg[1];
    *(bf16x8*)&Ks[krow * 104 + kcb + 16] = kreg[2];
#pragma unroll
    for (int i = 0; i < 3; i++) {
      int c = t + 256 * i;
      *(bf16x8*)&Vs[(c >> 3) * 104 + (c & 7) * 8] = vreg[i];
    }
    // prefetch next tile into regs (hidden under compute)
    if (kv0 + 64 < 1024) {
      int nx = kv0 + 64;
#pragma unroll
      for (int i = 0; i < 3; i++) {
        kreg[i] = *(const bf16x8*)(kbase + (size_t)(nx + krow) * 2304 + kcb + i * 8);
        int c = t + 256 * i;
        vreg[i] = *(const bf16x8*)(vbase + (size_t)(c >> 3) * 2048 + nx + (c & 7) * 8);
      }
    }
    __builtin_amdgcn_sched_barrier(0);
    __syncthreads();  // LDS ready

    // bias
    float4 bfv[4];
#pragma unroll
    for (int kvt = 0; kvt < 4; kvt++)
      bfv[kvt] = *(const float4*)(bp + kv0 + kvt * 16 + g * 4);

    // QK^T
    f32x4 s[4];
#pragma unroll
    for (int kvt = 0; kvt < 4; kvt++) {
      s[kvt] = zero;
#pragma unroll
      for (int f = 0; f < 3; f++) {
        bf16x8 kfr = *(const bf16x8*)&Ks[(kvt * 16 + fq) * 104 + f * 32 + g * 8];
        s[kvt] = __builtin_amdgcn_mfma_f32_16x16x32_bf16(kfr, qf[f], s[kvt], 0, 0, 0);
      }
    }

    // softmax + in-register P redistribution
    float p[4][4];
    float vmax = -1e30f;
#pragma unroll
    for (int kvt = 0; kvt < 4; kvt++)
#pragma unroll
      for (int r = 0; r < 4; r++) {
        float sv = fmaf(s[kvt][r], scale, (&bfv[kvt].x)[r]);
        p[kvt][r] = sv;
        vmax = fmaxf(vmax, sv);
      }
    vmax = fmaxf(vmax, __shfl_xor(vmax, 16));
    vmax = fmaxf(vmax, __shfl_xor(vmax, 32));
    if (!__all(vmax <= m_run + 8.0f)) {
      float m_new = fmaxf(m_run, vmax);
      float corr = exp2f((m_run - m_new) * LOG2E);
      l_run *= corr;
#pragma unroll
      for (int i = 0; i < 6; i++)
#pragma unroll
        for (int r = 0; r < 4; r++) o_acc[i][r] *= corr;
      m_run = m_new;
    }
    float rsum = 0.f;
    uint2 d[4];
#pragma unroll
    for (int kvt = 0; kvt < 4; kvt++) {
      float e0 = exp2f((p[kvt][0] - m_run) * LOG2E);
      float e1 = exp2f((p[kvt][1] - m_run) * LOG2E);
      float e2 = exp2f((p[kvt][2] - m_run) * LOG2E);
      float e3 = exp2f((p[kvt][3] - m_run) * LOG2E);
      rsum += (e0 + e1) + (e2 + e3);
      d[kvt].x = packbf2(e0, e1);
      d[kvt].y = packbf2(e2, e3);
    }
    rsum += __shfl_xor(rsum, 16);
    rsum += __shfl_xor(rsum, 32);
    l_run += rsum;

    // lane holds kv-quads {g,g+4,g+8,g+12}; PV needs {2g,2g+1} (kf=0), {8+2g,8+2g+1} (kf=1)
    bf16x8 pb[2];
    {
      bool glow = (g < 2);
      uint2 snd0 = glow ? d[1] : d[0];
      uint2 snd1 = glow ? d[3] : d[2];
      uint2 r0, r1;
      r0.x = __shfl_xor(snd0.x, 32); r0.y = __shfl_xor(snd0.y, 32);
      r1.x = __shfl_xor(snd1.x, 32); r1.y = __shfl_xor(snd1.y, 32);
      uint2 k0 = glow ? d[0] : d[1];
      uint2 k1 = glow ? d[2] : d[3];
      bool sendk = ((g ^ (g >> 1)) & 1);
      uint2 s0 = sendk ? k0 : r0;
      uint2 s1 = sendk ? k1 : r1;
      uint2 q0_, q1_;
      q0_.x = __shfl_xor(s0.x, 16); q0_.y = __shfl_xor(s0.y, 16);
      q1_.x = __shfl_xor(s1.x, 16); q1_.y = __shfl_xor(s1.y, 16);
      uint2 kept0 = sendk ? r0 : k0;
      uint2 kept1 = sendk ? r1 : k1;
      bool godd = (g & 1);
      uint2 lo0 = godd ? q0_ : kept0;
      uint2 hi0 = godd ? kept0 : q0_;
      uint2 lo1 = godd ? q1_ : kept1;
      uint2 hi1 = godd ? kept1 : q1_;
      uint4 u0 = { lo0.x, lo0.y, hi0.x, hi0.y };
      uint4 u1 = { lo1.x, lo1.y, hi1.x, hi1.y };
      pb[0] = __builtin_bit_cast(bf16x8, u0);
      pb[1] = __builtin_bit_cast(bf16x8, u1);
    }

    // PV
#pragma unroll
    for (int kf = 0; kf < 2; kf++) {
#pragma unroll
      for (int ht = 0; ht < 6; ht++) {
        bf16x8 vfr = *(const bf16x8*)&Vs[(ht * 16 + fq) * 104 + kf * 32 + g * 8];
        o_acc[ht] = __builtin_amdgcn_mfma_f32_16x16x32_bf16(vfr, pb[kf], o_acc[ht], 0, 0, 0);
      }
    }
  }

  // epilogue: un-normalized partials + (m,l)
  {
    int q = q0 + fq;
    float* op = opart + (size_t)half * (16 * 2048 * 96) + ((size_t)(b * 8 + h) * 2048 + q) * 96;
    float* mlp = ml + ((size_t)half * 32768 + (size_t)(b * 8 + h) * 2048 + q) * 2;
#pragma unroll
    for (int ht = 0; ht < 6; ht++)
      *(f32x4*)&op[ht * 16 + g * 4] = o_acc[ht];
    if (g == 0) { mlp[0] = m_run; mlp[1] = l_run; }
  }
}

// ---------------------------------------------------------------- combine kv-split partials -> ctx bf16
__launch_bounds__(256)
__global__ void attn_combine_kernel(const float* __restrict__ opart, const float* __restrict__ ml,
                                    bf16* __restrict__ ctx) {
  int idx = blockIdx.x * blockDim.x + threadIdx.x;
  if (idx >= 786432) return;
  int e = idx * 4;
  int bh = e / (2048 * 96);
  int rem = e - bh * (2048 * 96);
  int q = rem / 96;
  int hd = rem - q * 96;
  const float* op0 = opart;
  const float* op1 = opart + (size_t)16 * 2048 * 96;
  float4 o1 = *(const float4*)&op0[e];
  float4 o2 = *(const float4*)&op1[e];
  const float* ml0 = ml + (size_t)(bh * 2048 + q) * 2;
  const float* ml1 = ml0 + (size_t)32768 * 2;
  float m1 = ml0[0], l1 = ml0[1];
  float m2 = ml1[0], l2 = ml1[1];
  float M = fmaxf(m1, m2);
  float w1 = exp2f((m1 - M) * LOG2E);
  float w2 = exp2f((m2 - M) * LOG2E);
  float inv = 1.0f / (l1 * w1 + l2 * w2);
  int b = bh >> 3, h = bh & 7;
  bf16x4 o;
  o[0] = (bf16)((o1.x * w1 + o2.x * w2) * inv);
  o[1] = (bf16)((o1.y * w1 + o2.y * w2) * inv);
  o[2] = (bf16)((o1.z * w1 + o2.z * w2) * inv);
  o[3] = (bf16)((o1.w * w1 + o2.w * w2) * inv);
  *(bf16x4*)&ctx[((size_t)b * 2048 + q) * 768 + h * 96 + hd] = o;
}

// ---------------------------------------------------------------- LayerNorm (row = block); in may alias outf
__launch_bounds__(256)
__global__ void ln_kernel(const float* in, const float* __restrict__ gamma,
                          const float* __restrict__ beta, float* outf, bf16* outb) {
  const int row = blockIdx.x;
  const int t = threadIdx.x;
  const float* rp = in + (size_t)row * 768;
  float v[3];
#pragma unroll
  for (int i = 0; i < 3; i++) v[i] = rp[t + 256 * i];
  float s = v[0] + v[1] + v[2];
  float ss = v[0] * v[0] + v[1] * v[1] + v[2] * v[2];
#pragma unroll
  for (int off = 1; off < 64; off <<= 1) {
    s += __shfl_xor(s, off);
    ss += __shfl_xor(ss, off);
  }
  __shared__ float red[8];
  if ((t & 63) == 0) { red[(t >> 6) * 2] = s; red[(t >> 6) * 2 + 1] = ss; }
  __syncthreads();
  s = red[0] + red[2] + red[4] + red[6];
  ss = red[1] + red[3] + red[5] + red[7];
  float mu = s * (1.0f / 768.0f);
  float var = ss * (1.0f / 768.0f) - mu * mu;
  float rs = rsqrtf(var + 1e-5f);
#pragma unroll
  for (int i = 0; i < 3; i++) {
    int col = t + 256 * i;
    float y = (v[i] - mu) * rs * gamma[col] + beta[col];
    outf[(size_t)row * 768 + col] = y;
    if (outb) outb[(size_t)row * 768 + col] = (bf16)y;
  }
}

// ---------------------------------------------------------------- launch
extern "C" void kernel_launch(void* const* d_in, const int* in_sizes, int n_in,
                              void* d_out, int out_size, void* d_ws, size_t ws_size,
                              hipStream_t stream) {
  (void)in_sizes; (void)n_in; (void)out_size; (void)ws_size;
  const float* x     = (const float*)d_in[0];
  const float* ab    = (const float*)d_in[1];
  const float* w_qkv = (const float*)d_in[2];
  const float* b_qkv = (const float*)d_in[3];
  const float* w_out = (const float*)d_in[4];
  const float* b_out = (const float*)d_in[5];
  const float* W1    = (const float*)d_in[6];
  const float* b1    = (const float*)d_in[7];
  const float* W2    = (const float*)d_in[8];
  const float* b2    = (const float*)d_in[9];
  const float* g1    = (const float*)d_in[10];
  const float* be1   = (const float*)d_in[11];
  const float* g2    = (const float*)d_in[12];
  const float* be2   = (const float*)d_in[13];
  float* outf = (float*)d_out;

  char* p = (char*)d_ws;
  bf16* xb    = (bf16*)p;  p += (size_t)4096 * 768 * 2;
  bf16* qkv   = (bf16*)p;  p += (size_t)4096 * 2304 * 2;
  bf16* ctx   = (bf16*)p;  p += (size_t)4096 * 768 * 2;
  float* x1f  = (float*)p; p += (size_t)4096 * 768 * 4;     // aliased: vt during attn phase
  bf16* x1b   = (bf16*)p;  p += (size_t)4096 * 768 * 2;
  bf16* hbuf  = (bf16*)p;  p += (size_t)4096 * 2048 * 2;
  bf16* wqkvb = (bf16*)p;  p += (size_t)2304 * 768 * 2;
  bf16* woutb = (bf16*)p;  p += (size_t)768 * 768 * 2;
  bf16* w1b   = (bf16*)p;  p += (size_t)2048 * 768 * 2;
  bf16* w2b   = (bf16*)p;  p += (size_t)768 * 2048 * 2;
  float* opart = (float*)p; p += (size_t)2 * 16 * 2048 * 96 * 4;
  float* mlb   = (float*)p; p += (size_t)2 * 32768 * 2 * 4;
  bf16* vtb   = (bf16*)x1f;

  CastSegs segs;
  segs.src[0] = x;     segs.dst[0] = xb;
  segs.src[1] = w_qkv; segs.dst[1] = wqkvb;
  segs.src[2] = w_out; segs.dst[2] = woutb;
  segs.src[3] = W1;    segs.dst[3] = w1b;
  segs.src[4] = W2;    segs.dst[4] = w2b;
  fused_cast_kernel<<<2048, 256, 0, stream>>>(segs);

  // qkv = x @ in_proj_w^T + b ; V part written transposed to vtb
  gemm_kernel<3><<<dim3(18, 32), 256, 0, stream>>>(xb, wqkvb, b_qkv, vtb, qkv, 768, 2304);
  // attention (kv-split x2, f32 bias) + combine
  attn_kernel<<<dim3(32, 8, 4), 256, 0, stream>>>(qkv, vtb, ab, opart, mlb);
  attn_combine_kernel<<<3072, 256, 0, stream>>>(opart, mlb, ctx);
  // res1 = ctx @ out_w^T + out_b + x   (into d_out)
  gemmW_kernel<<<dim3(12, 32), 256, 0, stream>>>(ctx, woutb, b_out, x, outf, 768, 768);
  // x1 = LN(res1)
  ln_kernel<<<4096, 256, 0, stream>>>(outf, g1, be1, x1f, x1b);
  // h = gelu(x1 @ W1^T + b1)
  gemm_kernel<2><<<dim3(16, 32), 256, 0, stream>>>(x1b, w1b, b1, nullptr, hbuf, 768, 2048);
  // res2 = h @ W2^T + b2 + x1   (into d_out)
  gemmW_kernel<<<dim3(12, 32), 256, 0, stream>>>(hbuf, w2b, b2, x1f, outf, 2048, 768);
  // out = LN(res2), in place
  ln_kernel<<<4096, 256, 0, stream>>>(outf, g2, be2, outf, nullptr);
}

// Round 8
// 216.971 us; speedup vs baseline: 1.0328x; 1.0328x over previous
//
#include <hip/hip_runtime.h>
#include <hip/hip_bf16.h>
#include <math.h>

typedef __bf16 bf16;
typedef __attribute__((ext_vector_type(8))) __bf16 bf16x8;
typedef __attribute__((ext_vector_type(4))) __bf16 bf16x4;
typedef __attribute__((ext_vector_type(2))) __bf16 bf16x2;
typedef __attribute__((ext_vector_type(4))) float f32x4;

#define LOG2E 1.4426950408889634f

__device__ __forceinline__ void gload16(const bf16* g, bf16* l) {
  __builtin_amdgcn_global_load_lds(
      (const __attribute__((address_space(1))) void*)g,
      (__attribute__((address_space(3))) void*)l, 16, 0, 0);
}

__device__ __forceinline__ unsigned packbf2(float a, float b) {
  bf16x2 v = { (bf16)a, (bf16)b };
  return __builtin_bit_cast(unsigned, v);
}

// XCD-chunking swizzle: hw round-robins consecutive ids over 8 XCDs; remap so
// each XCD owns a contiguous tile range (L2 panel reuse). Requires nwg%8==0.
__device__ __forceinline__ int xcd_swz(int id, int nwg) {
  return (id & 7) * (nwg >> 3) + (id >> 3);
}

// ---------------------------------------------------------------- fused cast fp32 -> bf16 (5 tensors, 1 launch)
struct CastSegs { const float* src[5]; bf16* dst[5]; };

__global__ void fused_cast_kernel(CastSegs segs) {
  const int e0 = 786432, e1 = 1228800, e2 = 1376256, e3 = 1769472, e4 = 2162688;
  int i = blockIdx.x * blockDim.x + threadIdx.x;
  int stride = gridDim.x * blockDim.x;
  for (; i < e4; i += stride) {
    int s = 0, base = 0;
    if (i >= e0) { s = 1; base = e0; }
    if (i >= e1) { s = 2; base = e1; }
    if (i >= e2) { s = 3; base = e2; }
    if (i >= e3) { s = 4; base = e3; }
    float4 v = ((const float4*)segs.src[s])[i - base];
    bf16x4 o = { (bf16)v.x, (bf16)v.y, (bf16)v.z, (bf16)v.w };
    ((bf16x4*)segs.dst[s])[i - base] = o;
  }
}

// ---------------------------------------------------------------- GEMM 128x128 (m97 structure)
// MODE 0: out bf16 = acc + bias
// MODE 2: out bf16 = gelu_erf(acc + bias)
// MODE 3: qkv writer: cols <1536 -> bf16 to out; cols >=1536 (V) -> transposed to vt
template<int MODE>
__launch_bounds__(256)
__global__ void gemm_kernel(const bf16* __restrict__ A, const bf16* __restrict__ W,
                            const float* __restrict__ bias, bf16* __restrict__ vt,
                            void* __restrict__ out, int K, int O) {
  __shared__ bf16 As[128 * 64];
  __shared__ bf16 Bs[128 * 64];
  const int gx = gridDim.x;
  const int id = blockIdx.y * gx + blockIdx.x;
  const int swz = xcd_swz(id, gx * gridDim.y);
  const int n0 = (swz / gx) * 128;
  const int o0 = (swz % gx) * 128;
  const int t    = threadIdx.x;
  const int lane = t & 63;
  const int wave = t >> 6;
  const int wr = (wave >> 1) * 64;
  const int wc = (wave & 1) * 64;

  f32x4 zero = {0.f, 0.f, 0.f, 0.f};
  f32x4 acc[4][4];
#pragma unroll
  for (int m = 0; m < 4; m++)
#pragma unroll
    for (int n = 0; n < 4; n++) acc[m][n] = zero;

  const int fr  = lane & 15;
  const int fg8 = (lane >> 4) * 8;

  for (int k0 = 0; k0 < K; k0 += 64) {
    __syncthreads();
#pragma unroll
    for (int c = 0; c < 4; c++) {
      int f = c * 256 + t;
      int row = f >> 3;
      int col = (f & 7) * 8;
      gload16(&A[(size_t)(n0 + row) * K + k0 + col], &As[f * 8]);
      gload16(&W[(size_t)(o0 + row) * K + k0 + col], &Bs[f * 8]);
    }
    __syncthreads();
#pragma unroll
    for (int kf = 0; kf < 2; kf++) {
      bf16x8 a[4], b[4];
#pragma unroll
      for (int m = 0; m < 4; m++) a[m] = *(const bf16x8*)&As[(wr + m * 16 + fr) * 64 + kf * 32 + fg8];
#pragma unroll
      for (int n = 0; n < 4; n++) b[n] = *(const bf16x8*)&Bs[(wc + n * 16 + fr) * 64 + kf * 32 + fg8];
#pragma unroll
      for (int m = 0; m < 4; m++)
#pragma unroll
        for (int n = 0; n < 4; n++)
          acc[m][n] = __builtin_amdgcn_mfma_f32_16x16x32_bf16(a[m], b[n], acc[m][n], 0, 0, 0);
    }
  }

  const int fg4 = (lane >> 4) * 4;
#pragma unroll
  for (int m = 0; m < 4; m++) {
#pragma unroll
    for (int n = 0; n < 4; n++) {
      int col = o0 + wc + n * 16 + fr;
      float bv = bias[col];
      if constexpr (MODE == 3) {
        if (col >= 1536) {
          int c = col - 1536;
          int h = c / 96;
          int hd = c - h * 96;
          int row0 = n0 + wr + m * 16 + fg4;
          int b = row0 >> 11;
          int token = row0 & 2047;
          bf16x4 ov;
#pragma unroll
          for (int r = 0; r < 4; r++) ov[r] = (bf16)(acc[m][n][r] + bv);
          *(bf16x4*)&vt[((size_t)((b * 8 + h) * 96 + hd)) * 2048 + token] = ov;
          continue;
        }
      }
#pragma unroll
      for (int r = 0; r < 4; r++) {
        int row = n0 + wr + m * 16 + fg4 + r;
        float v = acc[m][n][r] + bv;
        if constexpr (MODE == 2) {
          v = 0.5f * v * (1.0f + erff(v * 0.70710678118654752f));
          ((bf16*)out)[(size_t)row * O + col] = (bf16)v;
        } else {
          ((bf16*)out)[(size_t)row * O + col] = (bf16)v;
        }
      }
    }
  }
}

// ---------------------------------------------------------------- GEMM 128x128 split-K x2: f32 partials (no bias)
// blockIdx.z = k-slice; writes out + z*4096*O. LN combines partials + bias + res.
__launch_bounds__(256)
__global__ void gemmSK_kernel(const bf16* __restrict__ A, const bf16* __restrict__ W,
                              float* __restrict__ out, int K, int O) {
  __shared__ bf16 As[128 * 64];
  __shared__ bf16 Bs[128 * 64];
  const int gx = gridDim.x;
  const int id = blockIdx.y * gx + blockIdx.x;
  const int swz = xcd_swz(id, gx * gridDim.y);
  const int n0 = (swz / gx) * 128;
  const int o0 = (swz % gx) * 128;
  const int t    = threadIdx.x;
  const int lane = t & 63;
  const int wave = t >> 6;
  const int wr = (wave >> 1) * 64;
  const int wc = (wave & 1) * 64;
  const int khalf = K >> 1;
  const int kbeg = blockIdx.z * khalf;

  f32x4 zero = {0.f, 0.f, 0.f, 0.f};
  f32x4 acc[4][4];
#pragma unroll
  for (int m = 0; m < 4; m++)
#pragma unroll
    for (int n = 0; n < 4; n++) acc[m][n] = zero;

  const int fr  = lane & 15;
  const int fg8 = (lane >> 4) * 8;

  for (int k0 = kbeg; k0 < kbeg + khalf; k0 += 64) {
    __syncthreads();
#pragma unroll
    for (int c = 0; c < 4; c++) {
      int f = c * 256 + t;
      int row = f >> 3;
      int col = (f & 7) * 8;
      gload16(&A[(size_t)(n0 + row) * K + k0 + col], &As[f * 8]);
      gload16(&W[(size_t)(o0 + row) * K + k0 + col], &Bs[f * 8]);
    }
    __syncthreads();
#pragma unroll
    for (int kf = 0; kf < 2; kf++) {
      bf16x8 a[4], b[4];
#pragma unroll
      for (int m = 0; m < 4; m++) a[m] = *(const bf16x8*)&As[(wr + m * 16 + fr) * 64 + kf * 32 + fg8];
#pragma unroll
      for (int n = 0; n < 4; n++) b[n] = *(const bf16x8*)&Bs[(wc + n * 16 + fr) * 64 + kf * 32 + fg8];
#pragma unroll
      for (int m = 0; m < 4; m++)
#pragma unroll
        for (int n = 0; n < 4; n++)
          acc[m][n] = __builtin_amdgcn_mfma_f32_16x16x32_bf16(a[m], b[n], acc[m][n], 0, 0, 0);
    }
  }

  float* op = out + (size_t)blockIdx.z * 4096 * O;
  const int fg4 = (lane >> 4) * 4;
#pragma unroll
  for (int m = 0; m < 4; m++) {
#pragma unroll
    for (int n = 0; n < 4; n++) {
      int col = o0 + wc + n * 16 + fr;
#pragma unroll
      for (int r = 0; r < 4; r++) {
        int row = n0 + wr + m * 16 + fg4 + r;
        op[(size_t)row * O + col] = acc[m][n][r];
      }
    }
  }
}

// ---------------------------------------------------------------- flash attention, kv-split x2
// 4 waves x 16 q = 64 q/block; 1D grid 1024 with XCD-grouped decode so the 8
// h-blocks sharing a bias tile land on one XCD (bias tile L2-resident).
// Single-buffered K/V LDS stride 104, reg-prefetch, in-reg P exchange, defer-max,
// setprio around MFMA clusters.
__launch_bounds__(256, 4)
__global__ void attn_kernel(const bf16* __restrict__ qkv, const bf16* __restrict__ vt,
                            const float* __restrict__ bias, float* __restrict__ opart,
                            float* __restrict__ ml) {
  __shared__ bf16 Ks[64 * 104];
  __shared__ bf16 Vs[96 * 104];
  const int t    = threadIdx.x;
  const int lane = t & 63;
  const int wave = t >> 6;
  // XCD-grouped decode: xcd = bid&7 owns groups [xcd*16, xcd*16+16) x all 8 heads
  const int bid = blockIdx.x;
  const int xcd = bid & 7, j = bid >> 3;
  const int h = j & 7;
  const int g_ = xcd * 16 + (j >> 3);
  const int qb = g_ & 31;
  const int bh = g_ >> 5;            // 0..3
  const int half = bh & 1, b = bh >> 1;
  const int kvstart = half * 1024;
  const int q0 = qb * 64 + wave * 16;
  const int fq = lane & 15;
  const int g  = lane >> 4;
  const size_t base = (size_t)b * 2048 * 2304;

  bf16x8 qf[3];
  {
    const bf16* qp = qkv + base + (size_t)(q0 + fq) * 2304 + h * 96;
#pragma unroll
    for (int f = 0; f < 3; f++) qf[f] = *(const bf16x8*)(qp + f * 32 + g * 8);
  }

  const int krow = t >> 2, kcb = (t & 3) * 24;
  const bf16* kbase = qkv + base + (size_t)kvstart * 2304 + 768 + h * 96;
  const bf16* vbase = vt + (size_t)((b * 8 + h) * 96) * 2048 + kvstart;

  bf16x8 kreg[3], vreg[3];
#pragma unroll
  for (int i = 0; i < 3; i++) {
    kreg[i] = *(const bf16x8*)(kbase + (size_t)krow * 2304 + kcb + i * 8);
    int c = t + 256 * i;
    vreg[i] = *(const bf16x8*)(vbase + (size_t)(c >> 3) * 2048 + (c & 7) * 8);
  }

  float m_run = -1e30f, l_run = 0.f;
  f32x4 zero = {0.f, 0.f, 0.f, 0.f};
  f32x4 o_acc[6];
#pragma unroll
  for (int i = 0; i < 6; i++) o_acc[i] = zero;

  const float scale = 0.10206207261596575f;  // 1/sqrt(96)
  const float* bp = bias + ((size_t)b * 2048 + q0 + fq) * 2048 + kvstart;

  for (int kv0 = 0; kv0 < 1024; kv0 += 64) {
    if (kv0) __syncthreads();
    *(bf16x8*)&Ks[krow * 104 + kcb]      = kreg[0];
    *(bf16x8*)&Ks[krow * 104 + kcb + 8]  = kreg[1];
    *(bf16x8*)&Ks[krow * 104 + kcb + 16] = kreg[2];
#pragma unroll
    for (int i = 0; i < 3; i++) {
      int c = t + 256 * i;
      *(bf16x8*)&Vs[(c >> 3) * 104 + (c & 7) * 8] = vreg[i];
    }
    if (kv0 + 64 < 1024) {
      int nx = kv0 + 64;
#pragma unroll
      for (int i = 0; i < 3; i++) {
        kreg[i] = *(const bf16x8*)(kbase + (size_t)(nx + krow) * 2304 + kcb + i * 8);
        int c = t + 256 * i;
        vreg[i] = *(const bf16x8*)(vbase + (size_t)(c >> 3) * 2048 + nx + (c & 7) * 8);
      }
    }
    __builtin_amdgcn_sched_barrier(0);
    __syncthreads();

    float4 bfv[4];
#pragma unroll
    for (int kvt = 0; kvt < 4; kvt++)
      bfv[kvt] = *(const float4*)(bp + kv0 + kvt * 16 + g * 4);

    f32x4 s[4];
    __builtin_amdgcn_s_setprio(1);
#pragma unroll
    for (int kvt = 0; kvt < 4; kvt++) {
      s[kvt] = zero;
#pragma unroll
      for (int f = 0; f < 3; f++) {
        bf16x8 kfr = *(const bf16x8*)&Ks[(kvt * 16 + fq) * 104 + f * 32 + g * 8];
        s[kvt] = __builtin_amdgcn_mfma_f32_16x16x32_bf16(kfr, qf[f], s[kvt], 0, 0, 0);
      }
    }
    __builtin_amdgcn_s_setprio(0);

    float p[4][4];
    float vmax = -1e30f;
#pragma unroll
    for (int kvt = 0; kvt < 4; kvt++)
#pragma unroll
      for (int r = 0; r < 4; r++) {
        float sv = fmaf(s[kvt][r], scale, (&bfv[kvt].x)[r]);
        p[kvt][r] = sv;
        vmax = fmaxf(vmax, sv);
      }
    vmax = fmaxf(vmax, __shfl_xor(vmax, 16));
    vmax = fmaxf(vmax, __shfl_xor(vmax, 32));
    if (!__all(vmax <= m_run + 8.0f)) {
      float m_new = fmaxf(m_run, vmax);
      float corr = exp2f((m_run - m_new) * LOG2E);
      l_run *= corr;
#pragma unroll
      for (int i = 0; i < 6; i++)
#pragma unroll
        for (int r = 0; r < 4; r++) o_acc[i][r] *= corr;
      m_run = m_new;
    }
    float rsum = 0.f;
    uint2 d[4];
#pragma unroll
    for (int kvt = 0; kvt < 4; kvt++) {
      float e0 = exp2f((p[kvt][0] - m_run) * LOG2E);
      float e1 = exp2f((p[kvt][1] - m_run) * LOG2E);
      float e2 = exp2f((p[kvt][2] - m_run) * LOG2E);
      float e3 = exp2f((p[kvt][3] - m_run) * LOG2E);
      rsum += (e0 + e1) + (e2 + e3);
      d[kvt].x = packbf2(e0, e1);
      d[kvt].y = packbf2(e2, e3);
    }
    rsum += __shfl_xor(rsum, 16);
    rsum += __shfl_xor(rsum, 32);
    l_run += rsum;

    bf16x8 pb[2];
    {
      bool glow = (g < 2);
      uint2 snd0 = glow ? d[1] : d[0];
      uint2 snd1 = glow ? d[3] : d[2];
      uint2 r0, r1;
      r0.x = __shfl_xor(snd0.x, 32); r0.y = __shfl_xor(snd0.y, 32);
      r1.x = __shfl_xor(snd1.x, 32); r1.y = __shfl_xor(snd1.y, 32);
      uint2 k0 = glow ? d[0] : d[1];
      uint2 k1 = glow ? d[2] : d[3];
      bool sendk = ((g ^ (g >> 1)) & 1);
      uint2 s0 = sendk ? k0 : r0;
      uint2 s1 = sendk ? k1 : r1;
      uint2 q0_, q1_;
      q0_.x = __shfl_xor(s0.x, 16); q0_.y = __shfl_xor(s0.y, 16);
      q1_.x = __shfl_xor(s1.x, 16); q1_.y = __shfl_xor(s1.y, 16);
      uint2 kept0 = sendk ? r0 : k0;
      uint2 kept1 = sendk ? r1 : k1;
      bool godd = (g & 1);
      uint2 lo0 = godd ? q0_ : kept0;
      uint2 hi0 = godd ? kept0 : q0_;
      uint2 lo1 = godd ? q1_ : kept1;
      uint2 hi1 = godd ? kept1 : q1_;
      uint4 u0 = { lo0.x, lo0.y, hi0.x, hi0.y };
      uint4 u1 = { lo1.x, lo1.y, hi1.x, hi1.y };
      pb[0] = __builtin_bit_cast(bf16x8, u0);
      pb[1] = __builtin_bit_cast(bf16x8, u1);
    }

    __builtin_amdgcn_s_setprio(1);
#pragma unroll
    for (int kf = 0; kf < 2; kf++) {
#pragma unroll
      for (int ht = 0; ht < 6; ht++) {
        bf16x8 vfr = *(const bf16x8*)&Vs[(ht * 16 + fq) * 104 + kf * 32 + g * 8];
        o_acc[ht] = __builtin_amdgcn_mfma_f32_16x16x32_bf16(vfr, pb[kf], o_acc[ht], 0, 0, 0);
      }
    }
    __builtin_amdgcn_s_setprio(0);
  }

  {
    int q = q0 + fq;
    float* op = opart + (size_t)half * (16 * 2048 * 96) + ((size_t)(b * 8 + h) * 2048 + q) * 96;
    float* mlp = ml + ((size_t)half * 32768 + (size_t)(b * 8 + h) * 2048 + q) * 2;
#pragma unroll
    for (int ht = 0; ht < 6; ht++)
      *(f32x4*)&op[ht * 16 + g * 4] = o_acc[ht];
    if (g == 0) { mlp[0] = m_run; mlp[1] = l_run; }
  }
}

// ---------------------------------------------------------------- combine kv-split partials -> ctx bf16
__launch_bounds__(256)
__global__ void attn_combine_kernel(const float* __restrict__ opart, const float* __restrict__ ml,
                                    bf16* __restrict__ ctx) {
  int idx = blockIdx.x * blockDim.x + threadIdx.x;
  if (idx >= 786432) return;
  int e = idx * 4;
  int bh = e / (2048 * 96);
  int rem = e - bh * (2048 * 96);
  int q = rem / 96;
  int hd = rem - q * 96;
  const float* op0 = opart;
  const float* op1 = opart + (size_t)16 * 2048 * 96;
  float4 o1 = *(const float4*)&op0[e];
  float4 o2 = *(const float4*)&op1[e];
  const float* ml0 = ml + (size_t)(bh * 2048 + q) * 2;
  const float* ml1 = ml0 + (size_t)32768 * 2;
  float m1 = ml0[0], l1 = ml0[1];
  float m2 = ml1[0], l2 = ml1[1];
  float M = fmaxf(m1, m2);
  float w1 = exp2f((m1 - M) * LOG2E);
  float w2 = exp2f((m2 - M) * LOG2E);
  float inv = 1.0f / (l1 * w1 + l2 * w2);
  int b = bh >> 3, h = bh & 7;
  bf16x4 o;
  o[0] = (bf16)((o1.x * w1 + o2.x * w2) * inv);
  o[1] = (bf16)((o1.y * w1 + o2.y * w2) * inv);
  o[2] = (bf16)((o1.z * w1 + o2.z * w2) * inv);
  o[3] = (bf16)((o1.w * w1 + o2.w * w2) * inv);
  *(bf16x4*)&ctx[((size_t)b * 2048 + q) * 768 + h * 96 + hd] = o;
}

// ---------------------------------------------------------------- LayerNorm fused combine:
// x = p0 + p1 + bias[col] + res; y = LN(x)*gamma+beta -> outf (+ optional outb)
__launch_bounds__(256)
__global__ void lnf_kernel(const float* __restrict__ p0, const float* __restrict__ p1,
                           const float* __restrict__ bias, const float* __restrict__ res,
                           const float* __restrict__ gamma, const float* __restrict__ beta,
                           float* __restrict__ outf, bf16* __restrict__ outb) {
  const int row = blockIdx.x;
  const int t = threadIdx.x;
  const size_t off = (size_t)row * 768;
  float v[3];
#pragma unroll
  for (int i = 0; i < 3; i++) {
    int col = t + 256 * i;
    v[i] = p0[off + col] + p1[off + col] + bias[col] + res[off + col];
  }
  float s = v[0] + v[1] + v[2];
  float ss = v[0] * v[0] + v[1] * v[1] + v[2] * v[2];
#pragma unroll
  for (int o = 1; o < 64; o <<= 1) {
    s += __shfl_xor(s, o);
    ss += __shfl_xor(ss, o);
  }
  __shared__ float red[8];
  if ((t & 63) == 0) { red[(t >> 6) * 2] = s; red[(t >> 6) * 2 + 1] = ss; }
  __syncthreads();
  s = red[0] + red[2] + red[4] + red[6];
  ss = red[1] + red[3] + red[5] + red[7];
  float mu = s * (1.0f / 768.0f);
  float var = ss * (1.0f / 768.0f) - mu * mu;
  float rs = rsqrtf(var + 1e-5f);
#pragma unroll
  for (int i = 0; i < 3; i++) {
    int col = t + 256 * i;
    float y = (v[i] - mu) * rs * gamma[col] + beta[col];
    outf[off + col] = y;
    if (outb) outb[off + col] = (bf16)y;
  }
}

// ---------------------------------------------------------------- launch
extern "C" void kernel_launch(void* const* d_in, const int* in_sizes, int n_in,
                              void* d_out, int out_size, void* d_ws, size_t ws_size,
                              hipStream_t stream) {
  (void)in_sizes; (void)n_in; (void)out_size; (void)ws_size;
  const float* x     = (const float*)d_in[0];
  const float* ab    = (const float*)d_in[1];
  const float* w_qkv = (const float*)d_in[2];
  const float* b_qkv = (const float*)d_in[3];
  const float* w_out = (const float*)d_in[4];
  const float* b_out = (const float*)d_in[5];
  const float* W1    = (const float*)d_in[6];
  const float* b1    = (const float*)d_in[7];
  const float* W2    = (const float*)d_in[8];
  const float* b2    = (const float*)d_in[9];
  const float* g1    = (const float*)d_in[10];
  const float* be1   = (const float*)d_in[11];
  const float* g2    = (const float*)d_in[12];
  const float* be2   = (const float*)d_in[13];
  float* outf = (float*)d_out;

  char* p = (char*)d_ws;
  bf16* xb    = (bf16*)p;  p += (size_t)4096 * 768 * 2;
  bf16* qkv   = (bf16*)p;  p += (size_t)4096 * 2304 * 2;
  bf16* ctx   = (bf16*)p;  p += (size_t)4096 * 768 * 2;
  float* x1f  = (float*)p; p += (size_t)4096 * 768 * 4;     // aliased: vt during attn phase
  bf16* x1b   = (bf16*)p;  p += (size_t)4096 * 768 * 2;
  bf16* hbuf  = (bf16*)p;  p += (size_t)4096 * 2048 * 2;
  bf16* wqkvb = (bf16*)p;  p += (size_t)2304 * 768 * 2;
  bf16* woutb = (bf16*)p;  p += (size_t)768 * 768 * 2;
  bf16* w1b   = (bf16*)p;  p += (size_t)2048 * 768 * 2;
  bf16* w2b   = (bf16*)p;  p += (size_t)768 * 2048 * 2;
  float* opart = (float*)p; p += (size_t)2 * 16 * 2048 * 96 * 4;  // 25.2 MB; reused as SK partials
  float* mlb   = (float*)p; p += (size_t)2 * 32768 * 2 * 4;
  bf16* vtb   = (bf16*)x1f;
  float* pSK  = opart;           // 2 x 4096*768 f32 = 25.17 MB, fits opart region

  CastSegs segs;
  segs.src[0] = x;     segs.dst[0] = xb;
  segs.src[1] = w_qkv; segs.dst[1] = wqkvb;
  segs.src[2] = w_out; segs.dst[2] = woutb;
  segs.src[3] = W1;    segs.dst[3] = w1b;
  segs.src[4] = W2;    segs.dst[4] = w2b;
  fused_cast_kernel<<<2048, 256, 0, stream>>>(segs);

  // qkv = x @ in_proj_w^T + b ; V part written transposed to vtb
  gemm_kernel<3><<<dim3(18, 32), 256, 0, stream>>>(xb, wqkvb, b_qkv, vtb, qkv, 768, 2304);
  // attention (kv-split x2, XCD-grouped 1D grid) + combine
  attn_kernel<<<1024, 256, 0, stream>>>(qkv, vtb, ab, opart, mlb);
  attn_combine_kernel<<<3072, 256, 0, stream>>>(opart, mlb, ctx);
  // outproj split-K x2 -> f32 partials (overwrites opart region; combine already consumed it)
  gemmSK_kernel<<<dim3(6, 32, 2), 256, 0, stream>>>(ctx, woutb, pSK, 768, 768);
  // x1 = LN(p0 + p1 + b_out + x)
  lnf_kernel<<<4096, 256, 0, stream>>>(pSK, pSK + (size_t)4096 * 768, b_out, x, g1, be1, x1f, x1b);
  // h = gelu(x1 @ W1^T + b1)
  gemm_kernel<2><<<dim3(16, 32), 256, 0, stream>>>(x1b, w1b, b1, nullptr, hbuf, 768, 2048);
  // FF2 split-K x2 -> f32 partials
  gemmSK_kernel<<<dim3(6, 32, 2), 256, 0, stream>>>(hbuf, w2b, pSK, 2048, 768);
  // out = LN(p0 + p1 + b2 + x1)
  lnf_kernel<<<4096, 256, 0, stream>>>(pSK, pSK + (size_t)4096 * 768, b2, x1f, g2, be2, outf, nullptr);
}